// Round 16
// baseline (272.507 us; speedup 1.0000x reference)
//
#include <hip/hip_runtime.h>
#include <hip/hip_bf16.h>

// MSARowAttentionWithPairBias — r15 + r11-proven 2-blocks/CU attention + XCD decode.
// S=128 R=256 CM=256 CZ=128 C=32 H=8.

namespace {
constexpr int S_ = 128, R_ = 256, CM_ = 256, CZ_ = 128, C_ = 32, H_ = 8;
constexpr int SR_ = S_ * R_;   // 32768
constexpr int RR_ = R_ * R_;   // 65536
constexpr float EPS_ = 1e-5f;
constexpr float ISC_ = 0.17677669529663687f;  // 1/sqrt(32), folded into q and pair-bias

// fp32 region (floats)
constexpr size_t OFF_WC  = 0;        // wct bf16 [H][128][256] = 131072 floats
constexpr size_t OFF_BC  = 131072;   // bc [H][128]
constexpr size_t OFF_BBP = 132096;   // bbp [H][128]
constexpr size_t F32_END = 133120;
constexpr size_t BF_BASE = F32_END * 4;  // bytes
constexpr size_t QKVG_ELEMS  = (size_t)H_ * SR_ * C_;  // 8,388,608 each
constexpr size_t CAT_ELEMS   = (size_t)SR_ * CM_;      // 8,388,608
constexpr size_t WBT_ELEMS   = (size_t)H_ * 128 * 128; // 131,072
constexpr size_t WOT_ELEMS   = (size_t)256 * 256;      // 65,536
constexpr size_t PAIRN_ELEMS = (size_t)RR_ * 128;      // 8,388,608
constexpr size_t MSAN_ELEMS  = (size_t)SR_ * 256;      // 8,388,608
constexpr size_t NEED_BYTES =
    BF_BASE +
    (4 * QKVG_ELEMS + CAT_ELEMS + WBT_ELEMS + WOT_ELEMS + PAIRN_ELEMS + MSAN_ELEMS) * 2;
}  // namespace

typedef unsigned short bf_t;
typedef short s8v __attribute__((ext_vector_type(8)));  // 8 bf16 = 4 VGPR
typedef float f4v __attribute__((ext_vector_type(4)));  // MFMA acc

__device__ __forceinline__ unsigned pk2(float lo, float hi) {
  __hip_bfloat162 t = __float22bfloat162_rn(float2{lo, hi});
  return *reinterpret_cast<unsigned*>(&t);
}
__device__ __forceinline__ bf_t pk1(float v) {
  __hip_bfloat16 t = __float2bfloat16(v);
  return *reinterpret_cast<bf_t*>(&t);
}
__device__ __forceinline__ float uplo(unsigned u) { return __uint_as_float(u << 16); }
__device__ __forceinline__ f4v mfma16(s8v a, s8v b, f4v c) {
  return __builtin_amdgcn_mfma_f32_16x16x32_bf16(a, b, c, 0, 0, 0);
}
__device__ __forceinline__ s8v ld8(const bf_t* p) { return *reinterpret_cast<const s8v*>(p); }

// ---------------- K1: merged norms + weight prep (one launch; serial blocks FIRST) ----------------
// b<4: bias reductions (4x4 sub-blocks); [4,8196): pair norm; [8196,12292): msa norm;
// [12292,13188): wide weight transforms.
__global__ __launch_bounds__(512) void prep_all_k(
    const float* __restrict__ pair, const float* __restrict__ msa,
    const float* __restrict__ lng_m, const float* __restrict__ lnb_m,
    const float* __restrict__ lng_p, const float* __restrict__ lnb_p,
    const float* __restrict__ Wq, const float* __restrict__ Wk, const float* __restrict__ Wv,
    const float* __restrict__ Wg, const float* __restrict__ Wb, const float* __restrict__ Wo,
    bf_t* __restrict__ pairN, bf_t* __restrict__ msaN, bf_t* __restrict__ wct,
    bf_t* __restrict__ wbt, bf_t* __restrict__ wot, float* __restrict__ bc,
    float* __restrict__ bbp) {
  int b = blockIdx.x;
  int tid = threadIdx.x;
  int lane = tid & 63;
  if (b < 4) {  // bias reductions (latency tail -> start first)
    int ob = b * 4 + (tid >> 7);  // 0..15
    int t = tid & 127;
    if (ob < H_) {
      int h = ob;
      int m = t >> 5, d = t & 31;
      const float* Wsrc = (m == 0) ? Wq : (m == 1) ? Wk : (m == 2) ? Wv : Wg;
      float scale = (m == 0) ? ISC_ : 1.0f;
      float bias = 0.f;
      for (int c = 0; c < CM_; c++)
        bias += lnb_m[h * CM_ + c] * Wsrc[((size_t)h * CM_ + c) * C_ + d];
      bc[h * 128 + t] = bias * scale;
    } else {
      int h = ob - H_;
      float bias = 0.f;
      for (int c = 0; c < CZ_; c++)
        bias += lnb_p[h * CZ_ + c] * Wb[((size_t)h * CZ_ + c) * S_ + t];
      bbp[h * 128 + t] = bias * ISC_;
    }
  } else if (b < 8196) {  // pair norm: 8 rows/block
    int row = (b - 4) * 8 + (tid >> 6);
    float2 v = reinterpret_cast<const float2*>(pair + (size_t)row * CZ_)[lane];
    float s = v.x + v.y;
    float s2 = v.x * v.x + v.y * v.y;
    for (int off = 32; off; off >>= 1) {
      s += __shfl_xor(s, off);
      s2 += __shfl_xor(s2, off);
    }
    float m = s / CZ_;
    float rs = rsqrtf(s2 / CZ_ - m * m + EPS_);
    reinterpret_cast<unsigned*>(pairN)[(size_t)row * 64 + lane] =
        pk2((v.x - m) * rs, (v.y - m) * rs);
  } else if (b < 12292) {  // msa norm: 8 rows/block
    int row = (b - 8196) * 8 + (tid >> 6);
    float4 v = reinterpret_cast<const float4*>(msa + (size_t)row * CM_)[lane];
    float s = v.x + v.y + v.z + v.w;
    float s2 = v.x * v.x + v.y * v.y + v.z * v.z + v.w * v.w;
    for (int off = 32; off; off >>= 1) {
      s += __shfl_xor(s, off);
      s2 += __shfl_xor(s2, off);
    }
    float m = s / CM_;
    float rs = rsqrtf(s2 / CM_ - m * m + EPS_);
    uint2 wv;
    wv.x = pk2((v.x - m) * rs, (v.y - m) * rs);
    wv.y = pk2((v.z - m) * rs, (v.w - m) * rs);
    reinterpret_cast<uint2*>(msaN)[(size_t)row * 64 + lane] = wv;
  } else {  // wide element-wise weight transforms
    int idx = (b - 12292) * 512 + tid;  // 0..458751
    if (idx < 262144) {
      int h = idx >> 15, rem = idx & 32767;
      int j = rem >> 8, c = rem & 255;
      int m = j >> 5, d = j & 31;
      const float* Wsrc = (m == 0) ? Wq : (m == 1) ? Wk : (m == 2) ? Wv : Wg;
      float scale = (m == 0) ? ISC_ : 1.0f;
      wct[idx] = pk1(lng_m[h * CM_ + c] * Wsrc[((size_t)h * CM_ + c) * C_ + d] * scale);
    } else if (idx < 262144 + 131072) {
      int i2 = idx - 262144;
      int h = i2 >> 14, rem = i2 & 16383;
      int t = rem >> 7, c = rem & 127;
      wbt[i2] = pk1(lng_p[h * CZ_ + c] * Wb[((size_t)h * CZ_ + c) * S_ + t] * ISC_);
    } else {
      int i3 = idx - 262144 - 131072;
      int n = i3 >> 8, k = i3 & 255;
      wot[i3] = pk1(Wo[(size_t)k * 256 + n]);
    }
  }
}

// ---------------- K3: qkvg projection via MFMA (r14 proven) ----------------
__global__ __launch_bounds__(512, 1) void qkvg_mfma_k(
    const bf_t* __restrict__ msaN, const bf_t* __restrict__ wct, const float* __restrict__ bc,
    bf_t* __restrict__ q, bf_t* __restrict__ k, bf_t* __restrict__ v, bf_t* __restrict__ g) {
  __shared__ bf_t sm_a[128 * 256];  // 64 KB
  __shared__ bf_t sm_w[128 * 256];  // 64 KB
  int ib = blockIdx.x;
  int tid = threadIdx.x;
  int w = tid >> 6, l = tid & 63;
  int l15 = l & 15, l4 = l >> 4;
  int iw = w >> 2, jw = w & 3;  // per-wave output tile: 64 i x 32 j
  int sr0 = ib * 128;
  int sx7 = l15 & 7;
#pragma unroll
  for (int rep = 0; rep < 8; rep++) {  // pure copy of msaN rows
    int flat = rep * 512 + tid;
    int row = flat >> 5, c = flat & 31;
    *reinterpret_cast<uint4*>(&sm_a[row * 256 + ((c ^ (row & 7)) << 3)]) =
        *reinterpret_cast<const uint4*>(msaN + (size_t)(sr0 + row) * 256 + c * 8);
  }
  for (int h = 0; h < H_; h++) {
    __syncthreads();
#pragma unroll
    for (int rep = 0; rep < 8; rep++) {
      int flat = rep * 512 + tid;
      int row = flat >> 5, c = flat & 31;
      *reinterpret_cast<uint4*>(&sm_w[row * 256 + ((c ^ (row & 7)) << 3)]) =
          *reinterpret_cast<const uint4*>(wct + ((size_t)h * 128 + row) * 256 + c * 8);
    }
    f4v acc[4][2];
#pragma unroll
    for (int jt = 0; jt < 2; jt++) {
      float bb = bc[h * 128 + jw * 32 + jt * 16 + l15];
#pragma unroll
      for (int it = 0; it < 4; it++) acc[it][jt] = f4v{bb, bb, bb, bb};
    }
    __syncthreads();
#pragma unroll
    for (int ks = 0; ks < 8; ks++) {
      int ch = ks * 4 + l4;
      s8v a[4], b[2];
#pragma unroll
      for (int it = 0; it < 4; it++)
        a[it] = ld8(&sm_a[(iw * 64 + it * 16 + l15) * 256 + ((ch ^ sx7) << 3)]);
#pragma unroll
      for (int jt = 0; jt < 2; jt++)
        b[jt] = ld8(&sm_w[(jw * 32 + jt * 16 + l15) * 256 + ((ch ^ sx7) << 3)]);
#pragma unroll
      for (int it = 0; it < 4; it++)
#pragma unroll
        for (int jt = 0; jt < 2; jt++) acc[it][jt] = mfma16(a[it], b[jt], acc[it][jt]);
    }
#pragma unroll
    for (int it = 0; it < 4; it++) {
#pragma unroll
      for (int jt = 0; jt < 2; jt++) {
        int j = jw * 32 + jt * 16 + l15;
        int m_ = j >> 5, d = j & 31;
        bf_t* dst = (m_ == 0) ? q : (m_ == 1) ? k : (m_ == 2) ? v : g;
#pragma unroll
        for (int r = 0; r < 4; r++) {
          int i = iw * 64 + it * 16 + l4 * 4 + r;
          float val = acc[it][jt][r];
          if (m_ == 3) val = 1.f / (1.f + __expf(-val));
          dst[((size_t)h * SR_ + sr0 + i) * C_ + d] = pk1(val);
        }
      }
    }
  }
}

// ---------------- K4: full-MFMA attention, 78-KB LDS -> 2 blocks/CU (r11-proven core) ----------------
// XCD-bijective decode (r14): all 8 heads + 4 s-slots of an s-window share an XCD.
// b[h,s,i,j] = pairproj[h, 2s+(i>>7), 2*(i&127)+(j>>7), j&127]
__global__ __launch_bounds__(512, 4) void attn_mfma_k(
    const bf_t* __restrict__ pairN, const bf_t* __restrict__ wbt,
    const float* __restrict__ bbp, const bf_t* __restrict__ qg, const bf_t* __restrict__ kg,
    const bf_t* __restrict__ vg, const bf_t* __restrict__ gg, bf_t* __restrict__ cat) {
  __shared__ bf_t sm_pn[256 * 64];   // pairN K-chunk (i x 64cz), swz   32 KB
  __shared__ bf_t sm_wt[64 * 64];    // wbt K-chunk (j x 64cz), swz      8 KB
  __shared__ bf_t sm_p[256 * 64];    // P (i x j_local), swz            32 KB
  __shared__ bf_t sm_vt[32 * 64];    // v^T tile (d x j), swz            4 KB
  __shared__ float sm_redm[4 * 64];
  __shared__ float sm_reds[4 * 64];  // total 79,872 B -> 2 blocks/CU

  // XCD-bijective (s,h) decode
  int b = blockIdx.x;
  int x = b & 7, tq = b >> 3;
  int round = tq >> 5, inner = tq & 31;
  int sl = inner >> 3, h = inner & 7;
  int s = (round * 8 + x) * 4 + sl;

  int tid = threadIdx.x;
  int w = tid >> 6, l = tid & 63;
  int l15 = l & 15, l4 = l >> 4, sx7 = l15 & 7;
  int iw = w >> 1, jw = w & 1, dw = w & 1;
  size_t base = ((size_t)h * SR_ + (size_t)s * R_) * C_;  // bf16 elems
  const bf_t* wbh = wbt + (size_t)h * 128 * 128;

  // q fragments in registers (pass-invariant, coalesced 16-row reads)
  s8v qa[4];
#pragma unroll
  for (int it = 0; it < 4; it++)
    qa[it] = ld8(&qg[base + (size_t)(iw * 64 + it * 16 + l15) * C_ + l4 * 8]);

  f4v accO[4];
#pragma unroll
  for (int it = 0; it < 4; it++) accO[it] = f4v{0.f, 0.f, 0.f, 0.f};

  for (int pass = 0; pass < 4; pass++) {
    int p = pass >> 1, jh = pass & 1;
    int j0 = p * 128 + jh * 64;
    // k frags issued EARLY (global, coalesced); in flight across staging
    s8v kb0 = ld8(&kg[base + (size_t)(j0 + jw * 32 + l15) * C_ + l4 * 8]);
    s8v kb1 = ld8(&kg[base + (size_t)(j0 + jw * 32 + 16 + l15) * C_ + l4 * 8]);
    __syncthreads();  // (A) prev AV done; vt/pn/wt reusable
    if (tid >= 256) {  // stage vT: transpose 64x32 -> 32x64 (read at AV, post-F)
      int t2 = tid - 256;
      int j = t2 >> 2, dc = t2 & 3;
      uint4 u = *reinterpret_cast<const uint4*>(vg + base + (size_t)(j0 + j) * C_ + dc * 8);
      unsigned uu[4] = {u.x, u.y, u.z, u.w};
#pragma unroll
      for (int e = 0; e < 8; e++) {
        int d = dc * 8 + e;
        bf_t val = (bf_t)((uu[e >> 1] >> ((e & 1) * 16)) & 0xffff);
        sm_vt[d * 64 + ((((j >> 3) ^ (d & 7)) << 3) + (j & 7))] = val;
      }
    }
    f4v acc[4][2];
    {
      float bb0 = bbp[h * 128 + jh * 64 + jw * 32 + l15];
      float bb1 = bbp[h * 128 + jh * 64 + jw * 32 + 16 + l15];
#pragma unroll
      for (int it = 0; it < 4; it++) {
        acc[it][0] = f4v{bb0, bb0, bb0, bb0};
        acc[it][1] = f4v{bb1, bb1, bb1, bb1};
      }
    }
    // ---- pair-bias GEMM: K=128 in 2 staged chunks of 64 (r11-proven) ----
#pragma unroll
    for (int kc = 0; kc < 2; kc++) {
#pragma unroll
      for (int rep = 0; rep < 4; rep++) {  // stage pN chunk (256 rows x 64 cz)
        int idx = rep * 512 + tid;
        int row = idx >> 3, c8 = idx & 7;
        int gr = (2 * s + (row >> 7)) * 256 + 2 * (row & 127) + p;
        *reinterpret_cast<uint4*>(&sm_pn[row * 64 + ((c8 ^ (row & 7)) << 3)]) =
            *reinterpret_cast<const uint4*>(pairN + (size_t)gr * 128 + kc * 64 + c8 * 8);
      }
      {  // stage wt chunk (64 rows x 64 cz)
        int row = tid >> 3, c8 = tid & 7;
        *reinterpret_cast<uint4*>(&sm_wt[row * 64 + ((c8 ^ (row & 7)) << 3)]) =
            *reinterpret_cast<const uint4*>(wbh + (size_t)(jh * 64 + row) * 128 + kc * 64 +
                                            c8 * 8);
      }
      __syncthreads();  // (B/D) chunk staged
#pragma unroll
      for (int ks = 0; ks < 2; ks++) {
        int ch = ks * 4 + l4;
        s8v a[4], b2[2];
#pragma unroll
        for (int it = 0; it < 4; it++)
          a[it] = ld8(&sm_pn[(iw * 64 + it * 16 + l15) * 64 + ((ch ^ sx7) << 3)]);
#pragma unroll
        for (int u = 0; u < 2; u++)
          b2[u] = ld8(&sm_wt[(jw * 32 + u * 16 + l15) * 64 + ((ch ^ sx7) << 3)]);
#pragma unroll
        for (int it = 0; it < 4; it++) {
          acc[it][0] = mfma16(a[it], b2[0], acc[it][0]);
          acc[it][1] = mfma16(a[it], b2[1], acc[it][1]);
        }
      }
      if (kc == 0) __syncthreads();  // (C) chunk0 consumed before restage
    }
    // ---- QK^T: q regs x k global frags ----
#pragma unroll
    for (int it = 0; it < 4; it++) {
      acc[it][0] = mfma16(qa[it], kb0, acc[it][0]);
      acc[it][1] = mfma16(qa[it], kb1, acc[it][1]);
    }
    // ---- softmax over i: per-wave max + rescaled sums (one barrier) ----
    float fac[2], mloc[2];
#pragma unroll
    for (int u = 0; u < 2; u++) {
      float m0 = -1e30f;
#pragma unroll
      for (int it = 0; it < 4; it++)
#pragma unroll
        for (int r = 0; r < 4; r++) m0 = fmaxf(m0, acc[it][u][r]);
      m0 = fmaxf(m0, __shfl_xor(m0, 16));
      m0 = fmaxf(m0, __shfl_xor(m0, 32));
      float s0 = 0.f;
#pragma unroll
      for (int it = 0; it < 4; it++)
#pragma unroll
        for (int r = 0; r < 4; r++) {
          float e = __expf(acc[it][u][r] - m0);
          acc[it][u][r] = e;
          s0 += e;
        }
      s0 += __shfl_xor(s0, 16);
      s0 += __shfl_xor(s0, 32);
      mloc[u] = m0;
      if (l < 16) {
        sm_redm[iw * 64 + jw * 32 + u * 16 + l] = m0;
        sm_reds[iw * 64 + jw * 32 + u * 16 + l] = s0;
      }
    }
    __syncthreads();  // (E) reductions visible
#pragma unroll
    for (int u = 0; u < 2; u++) {
      int jc = jw * 32 + u * 16 + l15;
      float M = fmaxf(fmaxf(sm_redm[jc], sm_redm[64 + jc]),
                      fmaxf(sm_redm[128 + jc], sm_redm[192 + jc]));
      float tot = 0.f;
#pragma unroll
      for (int gx = 0; gx < 4; gx++)
        tot += sm_reds[gx * 64 + jc] * __expf(sm_redm[gx * 64 + jc] - M);
      fac[u] = __expf(mloc[u] - M) / tot;
#pragma unroll
      for (int it = 0; it < 4; it++)
#pragma unroll
        for (int r = 0; r < 4; r++) {
          int i = iw * 64 + it * 16 + l4 * 4 + r;
          sm_p[i * 64 + ((((jc >> 3) ^ (i & 7)) << 3) + (jc & 7))] =
              pk1(acc[it][u][r] * fac[u]);
        }
    }
    __syncthreads();  // (F) P + vT ready
    // ---- AV: O += P.V  (K=64: 2 ksteps) ----
#pragma unroll
    for (int ks = 0; ks < 2; ks++) {
      int ch = ks * 4 + l4;
      s8v vb = ld8(&sm_vt[(dw * 16 + l15) * 64 + ((ch ^ sx7) << 3)]);
#pragma unroll
      for (int it = 0; it < 4; it++) {
        s8v pa = ld8(&sm_p[(iw * 64 + it * 16 + l15) * 64 + ((ch ^ sx7) << 3)]);
        accO[it] = mfma16(pa, vb, accO[it]);
      }
    }
  }
  // ---- epilogue: gate and write cat ----
#pragma unroll
  for (int it = 0; it < 4; it++) {
#pragma unroll
    for (int r = 0; r < 4; r++) {
      int i = iw * 64 + it * 16 + l4 * 4 + r;
      int d = dw * 16 + l15;
      float gf = uplo((unsigned)gg[base + (size_t)i * C_ + d]);
      cat[((size_t)s * R_ + i) * 256 + h * 32 + d] = pk1(accO[it][r] * gf);
    }
  }
}

// ---------------- K6: output projection via MFMA (r9 proven) ----------------
__global__ __launch_bounds__(512, 1) void out_mfma_k(const bf_t* __restrict__ cat,
                                                     const bf_t* __restrict__ wot,
                                                     const float* __restrict__ bo,
                                                     float* __restrict__ out) {
  __shared__ bf_t sm_a[128 * 256];  // 64 KB
  __shared__ bf_t sm_b[128 * 256];  // 64 KB
  int ib = blockIdx.x;
  int tid = threadIdx.x;
  int w = tid >> 6, l = tid & 63;
  int l15 = l & 15, l4 = l >> 4, sx7 = l15 & 7;
  int iw = w >> 2, jw = w & 3;  // 64 i x 32 n per wave
  int sr0 = ib * 128;
#pragma unroll
  for (int rep = 0; rep < 8; rep++) {  // stage A (cat) once
    int flat = rep * 512 + tid;
    int row = flat >> 5, c = flat & 31;
    *reinterpret_cast<uint4*>(&sm_a[row * 256 + ((c ^ (row & 7)) << 3)]) =
        *reinterpret_cast<const uint4*>(cat + (size_t)(sr0 + row) * 256 + c * 8);
  }
  for (int nb = 0; nb < 2; nb++) {
    __syncthreads();  // A ready (nb=0); prev sm_b readers done (nb=1)
#pragma unroll
    for (int rep = 0; rep < 8; rep++) {  // stage WoT rows nb*128..+128
      int flat = rep * 512 + tid;
      int row = flat >> 5, c = flat & 31;
      *reinterpret_cast<uint4*>(&sm_b[row * 256 + ((c ^ (row & 7)) << 3)]) =
          *reinterpret_cast<const uint4*>(wot + (size_t)(nb * 128 + row) * 256 + c * 8);
    }
    f4v acc[4][2];
#pragma unroll
    for (int jt = 0; jt < 2; jt++) {
      float bb = bo[nb * 128 + jw * 32 + jt * 16 + l15];
#pragma unroll
      for (int it = 0; it < 4; it++) acc[it][jt] = f4v{bb, bb, bb, bb};
    }
    __syncthreads();  // B ready
#pragma unroll
    for (int ks = 0; ks < 8; ks++) {
      int ch = ks * 4 + l4;
      s8v a[4], b[2];
#pragma unroll
      for (int it = 0; it < 4; it++)
        a[it] = ld8(&sm_a[(iw * 64 + it * 16 + l15) * 256 + ((ch ^ sx7) << 3)]);
#pragma unroll
      for (int jt = 0; jt < 2; jt++)
        b[jt] = ld8(&sm_b[(jw * 32 + jt * 16 + l15) * 256 + ((ch ^ sx7) << 3)]);
#pragma unroll
      for (int it = 0; it < 4; it++)
#pragma unroll
        for (int jt = 0; jt < 2; jt++) acc[it][jt] = mfma16(a[it], b[jt], acc[it][jt]);
    }
#pragma unroll
    for (int it = 0; it < 4; it++)
#pragma unroll
      for (int jt = 0; jt < 2; jt++) {
        int n = nb * 128 + jw * 32 + jt * 16 + l15;
#pragma unroll
        for (int r = 0; r < 4; r++) {
          int i = iw * 64 + it * 16 + l4 * 4 + r;
          out[(size_t)(sr0 + i) * 256 + n] = acc[it][jt][r];
        }
      }
  }
}

extern "C" void kernel_launch(void* const* d_in, const int* in_sizes, int n_in, void* d_out,
                              int out_size, void* d_ws, size_t ws_size, hipStream_t stream) {
  if (ws_size < NEED_BYTES) return;  // diagnostic clean-fail (absmax would read 0.1309)

  const float* msa = (const float*)d_in[0];
  const float* pair = (const float*)d_in[1];
  const float* lng_m = (const float*)d_in[2];
  const float* lnb_m = (const float*)d_in[3];
  const float* lng_p = (const float*)d_in[4];
  const float* lnb_p = (const float*)d_in[5];
  const float* Wq = (const float*)d_in[6];
  const float* Wk = (const float*)d_in[7];
  const float* Wv = (const float*)d_in[8];
  const float* Wg = (const float*)d_in[9];
  const float* Wb = (const float*)d_in[10];
  const float* Wo = (const float*)d_in[11];
  const float* bo = (const float*)d_in[12];
  float* out = (float*)d_out;
  float* ws = (float*)d_ws;

  bf_t* wct = (bf_t*)(ws + OFF_WC);
  float* bc = ws + OFF_BC;
  float* bbp = ws + OFF_BBP;
  bf_t* qb = (bf_t*)((char*)d_ws + BF_BASE);
  bf_t* kb = qb + QKVG_ELEMS;
  bf_t* vb = kb + QKVG_ELEMS;
  bf_t* gb = vb + QKVG_ELEMS;
  bf_t* cat = gb + QKVG_ELEMS;
  bf_t* wbt = cat + CAT_ELEMS;
  bf_t* wot = wbt + WBT_ELEMS;
  bf_t* pairN = wot + WOT_ELEMS;
  bf_t* msaN = pairN + PAIRN_ELEMS;

  prep_all_k<<<13188, 512, 0, stream>>>(pair, msa, lng_m, lnb_m, lng_p, lnb_p, Wq, Wk, Wv, Wg,
                                        Wb, Wo, pairN, msaN, wct, wbt, wot, bc, bbp);
  qkvg_mfma_k<<<SR_ / 128, 512, 0, stream>>>(msaN, wct, bc, qb, kb, vb, gb);
  attn_mfma_k<<<S_ * H_, 512, 0, stream>>>(pairN, wbt, bbp, qb, kb, vb, gb, cat);
  out_mfma_k<<<SR_ / 128, 512, 0, stream>>>(cat, wot, bo, out);
}

// Round 17
// 212.573 us; speedup vs baseline: 1.2819x; 1.2819x over previous
//
#include <hip/hip_runtime.h>
#include <hip/hip_bf16.h>

// MSARowAttentionWithPairBias — r15 pipeline + 16-wave (1024-thr) attention.
// S=128 R=256 CM=256 CZ=128 C=32 H=8.
// r16 lesson: (512,4) spilled (VGPR 64, 176MB scratch). 16 waves @ 1 block/CU
// gives 4 waves/SIMD with a 128-VGPR budget and ~70 live regs.

namespace {
constexpr int S_ = 128, R_ = 256, CM_ = 256, CZ_ = 128, C_ = 32, H_ = 8;
constexpr int SR_ = S_ * R_;   // 32768
constexpr int RR_ = R_ * R_;   // 65536
constexpr float EPS_ = 1e-5f;
constexpr float ISC_ = 0.17677669529663687f;  // 1/sqrt(32), folded into q and pair-bias

// fp32 region (floats)
constexpr size_t OFF_WC  = 0;        // wct bf16 [H][128][256] = 131072 floats
constexpr size_t OFF_BC  = 131072;   // bc [H][128]
constexpr size_t OFF_BBP = 132096;   // bbp [H][128]
constexpr size_t F32_END = 133120;
constexpr size_t BF_BASE = F32_END * 4;  // bytes
constexpr size_t QKVG_ELEMS  = (size_t)H_ * SR_ * C_;  // 8,388,608 each
constexpr size_t CAT_ELEMS   = (size_t)SR_ * CM_;      // 8,388,608
constexpr size_t WBT_ELEMS   = (size_t)H_ * 128 * 128; // 131,072
constexpr size_t WOT_ELEMS   = (size_t)256 * 256;      // 65,536
constexpr size_t PAIRN_ELEMS = (size_t)RR_ * 128;      // 8,388,608
constexpr size_t MSAN_ELEMS  = (size_t)SR_ * 256;      // 8,388,608
constexpr size_t NEED_BYTES =
    BF_BASE +
    (4 * QKVG_ELEMS + CAT_ELEMS + WBT_ELEMS + WOT_ELEMS + PAIRN_ELEMS + MSAN_ELEMS) * 2;
}  // namespace

typedef unsigned short bf_t;
typedef short s8v __attribute__((ext_vector_type(8)));  // 8 bf16 = 4 VGPR
typedef float f4v __attribute__((ext_vector_type(4)));  // MFMA acc

__device__ __forceinline__ unsigned pk2(float lo, float hi) {
  __hip_bfloat162 t = __float22bfloat162_rn(float2{lo, hi});
  return *reinterpret_cast<unsigned*>(&t);
}
__device__ __forceinline__ bf_t pk1(float v) {
  __hip_bfloat16 t = __float2bfloat16(v);
  return *reinterpret_cast<bf_t*>(&t);
}
__device__ __forceinline__ float uplo(unsigned u) { return __uint_as_float(u << 16); }
__device__ __forceinline__ f4v mfma16(s8v a, s8v b, f4v c) {
  return __builtin_amdgcn_mfma_f32_16x16x32_bf16(a, b, c, 0, 0, 0);
}
__device__ __forceinline__ s8v ld8(const bf_t* p) { return *reinterpret_cast<const s8v*>(p); }

// ---------------- K1: merged norms + weight prep (serial bias blocks first) ----------------
__global__ __launch_bounds__(512) void prep_all_k(
    const float* __restrict__ pair, const float* __restrict__ msa,
    const float* __restrict__ lng_m, const float* __restrict__ lnb_m,
    const float* __restrict__ lng_p, const float* __restrict__ lnb_p,
    const float* __restrict__ Wq, const float* __restrict__ Wk, const float* __restrict__ Wv,
    const float* __restrict__ Wg, const float* __restrict__ Wb, const float* __restrict__ Wo,
    bf_t* __restrict__ pairN, bf_t* __restrict__ msaN, bf_t* __restrict__ wct,
    bf_t* __restrict__ wbt, bf_t* __restrict__ wot, float* __restrict__ bc,
    float* __restrict__ bbp) {
  int b = blockIdx.x;
  int tid = threadIdx.x;
  int lane = tid & 63;
  if (b < 4) {  // bias reductions (latency tail -> start first)
    int ob = b * 4 + (tid >> 7);  // 0..15
    int t = tid & 127;
    if (ob < H_) {
      int h = ob;
      int m = t >> 5, d = t & 31;
      const float* Wsrc = (m == 0) ? Wq : (m == 1) ? Wk : (m == 2) ? Wv : Wg;
      float scale = (m == 0) ? ISC_ : 1.0f;
      float bias = 0.f;
      for (int c = 0; c < CM_; c++)
        bias += lnb_m[h * CM_ + c] * Wsrc[((size_t)h * CM_ + c) * C_ + d];
      bc[h * 128 + t] = bias * scale;
    } else {
      int h = ob - H_;
      float bias = 0.f;
      for (int c = 0; c < CZ_; c++)
        bias += lnb_p[h * CZ_ + c] * Wb[((size_t)h * CZ_ + c) * S_ + t];
      bbp[h * 128 + t] = bias * ISC_;
    }
  } else if (b < 8196) {  // pair norm: 8 rows/block
    int row = (b - 4) * 8 + (tid >> 6);
    float2 v = reinterpret_cast<const float2*>(pair + (size_t)row * CZ_)[lane];
    float s = v.x + v.y;
    float s2 = v.x * v.x + v.y * v.y;
    for (int off = 32; off; off >>= 1) {
      s += __shfl_xor(s, off);
      s2 += __shfl_xor(s2, off);
    }
    float m = s / CZ_;
    float rs = rsqrtf(s2 / CZ_ - m * m + EPS_);
    reinterpret_cast<unsigned*>(pairN)[(size_t)row * 64 + lane] =
        pk2((v.x - m) * rs, (v.y - m) * rs);
  } else if (b < 12292) {  // msa norm: 8 rows/block
    int row = (b - 8196) * 8 + (tid >> 6);
    float4 v = reinterpret_cast<const float4*>(msa + (size_t)row * CM_)[lane];
    float s = v.x + v.y + v.z + v.w;
    float s2 = v.x * v.x + v.y * v.y + v.z * v.z + v.w * v.w;
    for (int off = 32; off; off >>= 1) {
      s += __shfl_xor(s, off);
      s2 += __shfl_xor(s2, off);
    }
    float m = s / CM_;
    float rs = rsqrtf(s2 / CM_ - m * m + EPS_);
    uint2 wv;
    wv.x = pk2((v.x - m) * rs, (v.y - m) * rs);
    wv.y = pk2((v.z - m) * rs, (v.w - m) * rs);
    reinterpret_cast<uint2*>(msaN)[(size_t)row * 64 + lane] = wv;
  } else {  // wide element-wise weight transforms
    int idx = (b - 12292) * 512 + tid;  // 0..458751
    if (idx < 262144) {
      int h = idx >> 15, rem = idx & 32767;
      int j = rem >> 8, c = rem & 255;
      int m = j >> 5, d = j & 31;
      const float* Wsrc = (m == 0) ? Wq : (m == 1) ? Wk : (m == 2) ? Wv : Wg;
      float scale = (m == 0) ? ISC_ : 1.0f;
      wct[idx] = pk1(lng_m[h * CM_ + c] * Wsrc[((size_t)h * CM_ + c) * C_ + d] * scale);
    } else if (idx < 262144 + 131072) {
      int i2 = idx - 262144;
      int h = i2 >> 14, rem = i2 & 16383;
      int t = rem >> 7, c = rem & 127;
      wbt[i2] = pk1(lng_p[h * CZ_ + c] * Wb[((size_t)h * CZ_ + c) * S_ + t] * ISC_);
    } else {
      int i3 = idx - 262144 - 131072;
      int n = i3 >> 8, k = i3 & 255;
      wot[i3] = pk1(Wo[(size_t)k * 256 + n]);
    }
  }
}

// ---------------- K3: qkvg projection via MFMA (r14/r15 proven) ----------------
__global__ __launch_bounds__(512, 1) void qkvg_mfma_k(
    const bf_t* __restrict__ msaN, const bf_t* __restrict__ wct, const float* __restrict__ bc,
    bf_t* __restrict__ q, bf_t* __restrict__ k, bf_t* __restrict__ v, bf_t* __restrict__ g) {
  __shared__ bf_t sm_a[128 * 256];  // 64 KB
  __shared__ bf_t sm_w[128 * 256];  // 64 KB
  int ib = blockIdx.x;
  int tid = threadIdx.x;
  int w = tid >> 6, l = tid & 63;
  int l15 = l & 15, l4 = l >> 4;
  int iw = w >> 2, jw = w & 3;  // per-wave output tile: 64 i x 32 j
  int sr0 = ib * 128;
  int sx7 = l15 & 7;
#pragma unroll
  for (int rep = 0; rep < 8; rep++) {  // pure copy of msaN rows
    int flat = rep * 512 + tid;
    int row = flat >> 5, c = flat & 31;
    *reinterpret_cast<uint4*>(&sm_a[row * 256 + ((c ^ (row & 7)) << 3)]) =
        *reinterpret_cast<const uint4*>(msaN + (size_t)(sr0 + row) * 256 + c * 8);
  }
  for (int h = 0; h < H_; h++) {
    __syncthreads();
#pragma unroll
    for (int rep = 0; rep < 8; rep++) {
      int flat = rep * 512 + tid;
      int row = flat >> 5, c = flat & 31;
      *reinterpret_cast<uint4*>(&sm_w[row * 256 + ((c ^ (row & 7)) << 3)]) =
          *reinterpret_cast<const uint4*>(wct + ((size_t)h * 128 + row) * 256 + c * 8);
    }
    f4v acc[4][2];
#pragma unroll
    for (int jt = 0; jt < 2; jt++) {
      float bb = bc[h * 128 + jw * 32 + jt * 16 + l15];
#pragma unroll
      for (int it = 0; it < 4; it++) acc[it][jt] = f4v{bb, bb, bb, bb};
    }
    __syncthreads();
#pragma unroll
    for (int ks = 0; ks < 8; ks++) {
      int ch = ks * 4 + l4;
      s8v a[4], b[2];
#pragma unroll
      for (int it = 0; it < 4; it++)
        a[it] = ld8(&sm_a[(iw * 64 + it * 16 + l15) * 256 + ((ch ^ sx7) << 3)]);
#pragma unroll
      for (int jt = 0; jt < 2; jt++)
        b[jt] = ld8(&sm_w[(jw * 32 + jt * 16 + l15) * 256 + ((ch ^ sx7) << 3)]);
#pragma unroll
      for (int it = 0; it < 4; it++)
#pragma unroll
        for (int jt = 0; jt < 2; jt++) acc[it][jt] = mfma16(a[it], b[jt], acc[it][jt]);
    }
#pragma unroll
    for (int it = 0; it < 4; it++) {
#pragma unroll
      for (int jt = 0; jt < 2; jt++) {
        int j = jw * 32 + jt * 16 + l15;
        int m_ = j >> 5, d = j & 31;
        bf_t* dst = (m_ == 0) ? q : (m_ == 1) ? k : (m_ == 2) ? v : g;
#pragma unroll
        for (int r = 0; r < 4; r++) {
          int i = iw * 64 + it * 16 + l4 * 4 + r;
          float val = acc[it][jt][r];
          if (m_ == 3) val = 1.f / (1.f + __expf(-val));
          dst[((size_t)h * SR_ + sr0 + i) * C_ + d] = pk1(val);
        }
      }
    }
  }
}

// ---------------- K4: full-MFMA attention, 16 waves (1024 thr), 1 block/CU ----------------
// XCD-bijective decode (r14). Per wave: 32 i-rows x 32 j-cols. r15 sync structure.
// b[h,s,i,j] = pairproj[h, 2s+(i>>7), 2*(i&127)+(j>>7), j&127]
__global__ __launch_bounds__(1024, 4) void attn_mfma_k(
    const bf_t* __restrict__ pairN, const bf_t* __restrict__ wbt,
    const float* __restrict__ bbp, const bf_t* __restrict__ qg, const bf_t* __restrict__ kg,
    const bf_t* __restrict__ vg, const bf_t* __restrict__ gg, bf_t* __restrict__ cat) {
  __shared__ bf_t sm_pN[256 * 128];  // pair rows (i x cz), swz   64.0 KB
  __shared__ bf_t sm_wt[64 * 128];   // WbpT tile (j x cz), swz   16.0 KB
  __shared__ bf_t sm_p[256 * 64];    // P (i x j_local), swz      32.0 KB
  __shared__ bf_t sm_vt[32 * 64];    // v^T tile (d x j), swz      4.0 KB
  __shared__ float sm_redm[8 * 64];  // 2.0 KB
  __shared__ float sm_reds[8 * 64];  // 2.0 KB   total 120.0 KB -> 1 block/CU, 16 waves

  // XCD-bijective (s,h) decode
  int b = blockIdx.x;
  int x = b & 7, tq = b >> 3;
  int round = tq >> 5, inner = tq & 31;
  int sl = inner >> 3, h = inner & 7;
  int s = (round * 8 + x) * 4 + sl;

  int tid = threadIdx.x;
  int w = tid >> 6, l = tid & 63;
  int l15 = l & 15, l4 = l >> 4, sx7 = l15 & 7;
  int iw = w >> 1, jw = w & 1, dw = w & 1;  // 8 row-groups x {2 col / 2 d} groups
  size_t base = ((size_t)h * SR_ + (size_t)s * R_) * C_;  // bf16 elems

  // q fragments in registers (pass-invariant, coalesced 16-row reads)
  s8v qa[2];
#pragma unroll
  for (int it = 0; it < 2; it++)
    qa[it] = ld8(&qg[base + (size_t)(iw * 32 + it * 16 + l15) * C_ + l4 * 8]);

  f4v accO[2];
#pragma unroll
  for (int it = 0; it < 2; it++) accO[it] = f4v{0.f, 0.f, 0.f, 0.f};

  for (int p = 0; p < 2; p++) {
    __syncthreads();  // (A) prev readers of pN done
    // ---- stage pN: pure bf16 copy, 256 rows x 16 chunks (4 reps x 1024 thr) ----
#pragma unroll
    for (int rep = 0; rep < 4; rep++) {
      int flat = rep * 1024 + tid;
      int row = flat >> 4, c = flat & 15;
      int gr = (2 * s + (row >> 7)) * 256 + 2 * (row & 127) + p;
      *reinterpret_cast<uint4*>(&sm_pN[row * 128 + ((c ^ (row & 7)) << 3)]) =
          *reinterpret_cast<const uint4*>(pairN + (size_t)gr * 128 + c * 8);
    }
    for (int jh = 0; jh < 2; jh++) {
      int j0 = p * 128 + jh * 64;
      // k frags issued EARLY (global, coalesced); in flight across staging
      s8v kb0 = ld8(&kg[base + (size_t)(j0 + jw * 32 + l15) * C_ + l4 * 8]);
      s8v kb1 = ld8(&kg[base + (size_t)(j0 + jw * 32 + 16 + l15) * C_ + l4 * 8]);
      __syncthreads();  // (B) pN ready; prev AV readers of wt/vt done
      {                 // stage WtT: 64 rows x 16 chunks (1 uint4/thread)
        int row = tid >> 4, c = tid & 15;
        *reinterpret_cast<uint4*>(&sm_wt[row * 128 + ((c ^ (row & 7)) << 3)]) =
            *reinterpret_cast<const uint4*>(wbt + ((size_t)h * 128 + jh * 64 + row) * 128 +
                                            c * 8);
      }
      if (tid < 256) {  // stage vT: transpose 64x32 -> 32x64
        int j = tid >> 2, dc = tid & 3;
        uint4 u = *reinterpret_cast<const uint4*>(vg + base + (size_t)(j0 + j) * C_ + dc * 8);
        unsigned uu[4] = {u.x, u.y, u.z, u.w};
#pragma unroll
        for (int e = 0; e < 8; e++) {
          int d = dc * 8 + e;
          bf_t val = (bf_t)((uu[e >> 1] >> ((e & 1) * 16)) & 0xffff);
          sm_vt[d * 64 + ((((j >> 3) ^ (d & 7)) << 3) + (j & 7))] = val;
        }
      }
      // init acc with pair-bias column term
      f4v acc[2][2];
      {
        float bb0 = bbp[h * 128 + jh * 64 + jw * 32 + l15];
        float bb1 = bbp[h * 128 + jh * 64 + jw * 32 + 16 + l15];
#pragma unroll
        for (int it = 0; it < 2; it++) {
          acc[it][0] = f4v{bb0, bb0, bb0, bb0};
          acc[it][1] = f4v{bb1, bb1, bb1, bb1};
        }
      }
      __syncthreads();  // (C) staging ready
      // ---- pair-bias GEMM: K=128 (4 ksteps) ----
#pragma unroll
      for (int ks = 0; ks < 4; ks++) {
        int ch = (ks * 4 + l4);
        s8v a[2], b2[2];
#pragma unroll
        for (int it = 0; it < 2; it++)
          a[it] = ld8(&sm_pN[(iw * 32 + it * 16 + l15) * 128 + ((ch ^ sx7) << 3)]);
#pragma unroll
        for (int u = 0; u < 2; u++)
          b2[u] = ld8(&sm_wt[(jw * 32 + u * 16 + l15) * 128 + ((ch ^ sx7) << 3)]);
#pragma unroll
        for (int it = 0; it < 2; it++) {
          acc[it][0] = mfma16(a[it], b2[0], acc[it][0]);
          acc[it][1] = mfma16(a[it], b2[1], acc[it][1]);
        }
      }
      // ---- QK^T: q regs x k global frags ----
#pragma unroll
      for (int it = 0; it < 2; it++) {
        acc[it][0] = mfma16(qa[it], kb0, acc[it][0]);
        acc[it][1] = mfma16(qa[it], kb1, acc[it][1]);
      }
      // ---- softmax over i: per-wave max + rescaled sums (ONE barrier) ----
      float fac[2], mloc[2];
#pragma unroll
      for (int u = 0; u < 2; u++) {
        float m0 = -1e30f;
#pragma unroll
        for (int it = 0; it < 2; it++)
#pragma unroll
          for (int r = 0; r < 4; r++) m0 = fmaxf(m0, acc[it][u][r]);
        m0 = fmaxf(m0, __shfl_xor(m0, 16));
        m0 = fmaxf(m0, __shfl_xor(m0, 32));
        float s0 = 0.f;
#pragma unroll
        for (int it = 0; it < 2; it++)
#pragma unroll
          for (int r = 0; r < 4; r++) {
            float e = __expf(acc[it][u][r] - m0);
            acc[it][u][r] = e;
            s0 += e;
          }
        s0 += __shfl_xor(s0, 16);
        s0 += __shfl_xor(s0, 32);
        mloc[u] = m0;
        if (l < 16) {
          sm_redm[iw * 64 + jw * 32 + u * 16 + l] = m0;
          sm_reds[iw * 64 + jw * 32 + u * 16 + l] = s0;
        }
      }
      __syncthreads();  // (E) reductions visible
#pragma unroll
      for (int u = 0; u < 2; u++) {
        int jc = jw * 32 + u * 16 + l15;
        float M = -1e30f;
#pragma unroll
        for (int gx = 0; gx < 8; gx++) M = fmaxf(M, sm_redm[gx * 64 + jc]);
        float tot = 0.f;
#pragma unroll
        for (int gx = 0; gx < 8; gx++)
          tot += sm_reds[gx * 64 + jc] * __expf(sm_redm[gx * 64 + jc] - M);
        fac[u] = __expf(mloc[u] - M) / tot;
#pragma unroll
        for (int it = 0; it < 2; it++)
#pragma unroll
          for (int r = 0; r < 4; r++) {
            int i = iw * 32 + it * 16 + l4 * 4 + r;
            sm_p[i * 64 + ((((jc >> 3) ^ (i & 7)) << 3) + (jc & 7))] =
                pk1(acc[it][u][r] * fac[u]);
          }
      }
      __syncthreads();  // (F) P + vT ready
      // ---- AV: O += P.V  (K=64: 2 ksteps) ----
#pragma unroll
      for (int ks = 0; ks < 2; ks++) {
        int ch = ks * 4 + l4;
        s8v vb = ld8(&sm_vt[(dw * 16 + l15) * 64 + ((ch ^ sx7) << 3)]);
#pragma unroll
        for (int it = 0; it < 2; it++) {
          s8v pa = ld8(&sm_p[(iw * 32 + it * 16 + l15) * 64 + ((ch ^ sx7) << 3)]);
          accO[it] = mfma16(pa, vb, accO[it]);
        }
      }
    }
  }
  // ---- epilogue: gate and write cat ----
#pragma unroll
  for (int it = 0; it < 2; it++) {
#pragma unroll
    for (int r = 0; r < 4; r++) {
      int i = iw * 32 + it * 16 + l4 * 4 + r;
      int d = dw * 16 + l15;
      float gf = uplo((unsigned)gg[base + (size_t)i * C_ + d]);
      cat[((size_t)s * R_ + i) * 256 + h * 32 + d] = pk1(accO[it][r] * gf);
    }
  }
}

// ---------------- K6: output projection via MFMA (r9 proven) ----------------
__global__ __launch_bounds__(512, 1) void out_mfma_k(const bf_t* __restrict__ cat,
                                                     const bf_t* __restrict__ wot,
                                                     const float* __restrict__ bo,
                                                     float* __restrict__ out) {
  __shared__ bf_t sm_a[128 * 256];  // 64 KB
  __shared__ bf_t sm_b[128 * 256];  // 64 KB
  int ib = blockIdx.x;
  int tid = threadIdx.x;
  int w = tid >> 6, l = tid & 63;
  int l15 = l & 15, l4 = l >> 4, sx7 = l15 & 7;
  int iw = w >> 2, jw = w & 3;  // 64 i x 32 n per wave
  int sr0 = ib * 128;
#pragma unroll
  for (int rep = 0; rep < 8; rep++) {  // stage A (cat) once
    int flat = rep * 512 + tid;
    int row = flat >> 5, c = flat & 31;
    *reinterpret_cast<uint4*>(&sm_a[row * 256 + ((c ^ (row & 7)) << 3)]) =
        *reinterpret_cast<const uint4*>(cat + (size_t)(sr0 + row) * 256 + c * 8);
  }
  for (int nb = 0; nb < 2; nb++) {
    __syncthreads();  // A ready (nb=0); prev sm_b readers done (nb=1)
#pragma unroll
    for (int rep = 0; rep < 8; rep++) {  // stage WoT rows nb*128..+128
      int flat = rep * 512 + tid;
      int row = flat >> 5, c = flat & 31;
      *reinterpret_cast<uint4*>(&sm_b[row * 256 + ((c ^ (row & 7)) << 3)]) =
          *reinterpret_cast<const uint4*>(wot + (size_t)(nb * 128 + row) * 256 + c * 8);
    }
    f4v acc[4][2];
#pragma unroll
    for (int jt = 0; jt < 2; jt++) {
      float bb = bo[nb * 128 + jw * 32 + jt * 16 + l15];
#pragma unroll
      for (int it = 0; it < 4; it++) acc[it][jt] = f4v{bb, bb, bb, bb};
    }
    __syncthreads();  // B ready
#pragma unroll
    for (int ks = 0; ks < 8; ks++) {
      int ch = ks * 4 + l4;
      s8v a[4], b[2];
#pragma unroll
      for (int it = 0; it < 4; it++)
        a[it] = ld8(&sm_a[(iw * 64 + it * 16 + l15) * 256 + ((ch ^ sx7) << 3)]);
#pragma unroll
      for (int jt = 0; jt < 2; jt++)
        b[jt] = ld8(&sm_b[(jw * 32 + jt * 16 + l15) * 256 + ((ch ^ sx7) << 3)]);
#pragma unroll
      for (int it = 0; it < 4; it++)
#pragma unroll
        for (int jt = 0; jt < 2; jt++) acc[it][jt] = mfma16(a[it], b[jt], acc[it][jt]);
    }
#pragma unroll
    for (int it = 0; it < 4; it++)
#pragma unroll
      for (int jt = 0; jt < 2; jt++) {
        int n = nb * 128 + jw * 32 + jt * 16 + l15;
#pragma unroll
        for (int r = 0; r < 4; r++) {
          int i = iw * 64 + it * 16 + l4 * 4 + r;
          out[(size_t)(sr0 + i) * 256 + n] = acc[it][jt][r];
        }
      }
  }
}

extern "C" void kernel_launch(void* const* d_in, const int* in_sizes, int n_in, void* d_out,
                              int out_size, void* d_ws, size_t ws_size, hipStream_t stream) {
  if (ws_size < NEED_BYTES) return;  // diagnostic clean-fail (absmax would read 0.1309)

  const float* msa = (const float*)d_in[0];
  const float* pair = (const float*)d_in[1];
  const float* lng_m = (const float*)d_in[2];
  const float* lnb_m = (const float*)d_in[3];
  const float* lng_p = (const float*)d_in[4];
  const float* lnb_p = (const float*)d_in[5];
  const float* Wq = (const float*)d_in[6];
  const float* Wk = (const float*)d_in[7];
  const float* Wv = (const float*)d_in[8];
  const float* Wg = (const float*)d_in[9];
  const float* Wb = (const float*)d_in[10];
  const float* Wo = (const float*)d_in[11];
  const float* bo = (const float*)d_in[12];
  float* out = (float*)d_out;
  float* ws = (float*)d_ws;

  bf_t* wct = (bf_t*)(ws + OFF_WC);
  float* bc = ws + OFF_BC;
  float* bbp = ws + OFF_BBP;
  bf_t* qb = (bf_t*)((char*)d_ws + BF_BASE);
  bf_t* kb = qb + QKVG_ELEMS;
  bf_t* vb = kb + QKVG_ELEMS;
  bf_t* gb = vb + QKVG_ELEMS;
  bf_t* cat = gb + QKVG_ELEMS;
  bf_t* wbt = cat + CAT_ELEMS;
  bf_t* wot = wbt + WBT_ELEMS;
  bf_t* pairN = wot + WOT_ELEMS;
  bf_t* msaN = pairN + PAIRN_ELEMS;

  prep_all_k<<<13188, 512, 0, stream>>>(pair, msa, lng_m, lnb_m, lng_p, lnb_p, Wq, Wk, Wv, Wg,
                                        Wb, Wo, pairN, msaN, wct, wbt, wot, bc, bbp);
  qkvg_mfma_k<<<SR_ / 128, 512, 0, stream>>>(msaN, wct, bc, qb, kb, vb, gb);
  attn_mfma_k<<<S_ * H_, 1024, 0, stream>>>(pairN, wbt, bbp, qb, kb, vb, gb, cat);
  out_mfma_k<<<SR_ / 128, 512, 0, stream>>>(cat, wot, bo, out);
}

// Round 18
// 157.390 us; speedup vs baseline: 1.7314x; 1.3506x over previous
//
#include <hip/hip_runtime.h>
#include <hip/hip_bf16.h>

// MSARowAttentionWithPairBias — r16 with the launch_bounds fix: (512,2).
// Empirical finding (r3/r11/r16/r17): 2nd __launch_bounds__ arg acts as min
// BLOCKS/CU on this toolchain; (512,4) and (1024,4) forced 64-VGPR spills.
// (512,2) -> 4 waves/SIMD, 128-VGPR budget, no spill (r3 precedent: 88 VGPR).
// S=128 R=256 CM=256 CZ=128 C=32 H=8.

namespace {
constexpr int S_ = 128, R_ = 256, CM_ = 256, CZ_ = 128, C_ = 32, H_ = 8;
constexpr int SR_ = S_ * R_;   // 32768
constexpr int RR_ = R_ * R_;   // 65536
constexpr float EPS_ = 1e-5f;
constexpr float ISC_ = 0.17677669529663687f;  // 1/sqrt(32), folded into q and pair-bias

// fp32 region (floats)
constexpr size_t OFF_WC  = 0;        // wct bf16 [H][128][256] = 131072 floats
constexpr size_t OFF_BC  = 131072;   // bc [H][128]
constexpr size_t OFF_BBP = 132096;   // bbp [H][128]
constexpr size_t F32_END = 133120;
constexpr size_t BF_BASE = F32_END * 4;  // bytes
constexpr size_t QKVG_ELEMS  = (size_t)H_ * SR_ * C_;  // 8,388,608 each
constexpr size_t CAT_ELEMS   = (size_t)SR_ * CM_;      // 8,388,608
constexpr size_t WBT_ELEMS   = (size_t)H_ * 128 * 128; // 131,072
constexpr size_t WOT_ELEMS   = (size_t)256 * 256;      // 65,536
constexpr size_t PAIRN_ELEMS = (size_t)RR_ * 128;      // 8,388,608
constexpr size_t MSAN_ELEMS  = (size_t)SR_ * 256;      // 8,388,608
constexpr size_t NEED_BYTES =
    BF_BASE +
    (4 * QKVG_ELEMS + CAT_ELEMS + WBT_ELEMS + WOT_ELEMS + PAIRN_ELEMS + MSAN_ELEMS) * 2;
}  // namespace

typedef unsigned short bf_t;
typedef short s8v __attribute__((ext_vector_type(8)));  // 8 bf16 = 4 VGPR
typedef float f4v __attribute__((ext_vector_type(4)));  // MFMA acc

__device__ __forceinline__ unsigned pk2(float lo, float hi) {
  __hip_bfloat162 t = __float22bfloat162_rn(float2{lo, hi});
  return *reinterpret_cast<unsigned*>(&t);
}
__device__ __forceinline__ bf_t pk1(float v) {
  __hip_bfloat16 t = __float2bfloat16(v);
  return *reinterpret_cast<bf_t*>(&t);
}
__device__ __forceinline__ float uplo(unsigned u) { return __uint_as_float(u << 16); }
__device__ __forceinline__ f4v mfma16(s8v a, s8v b, f4v c) {
  return __builtin_amdgcn_mfma_f32_16x16x32_bf16(a, b, c, 0, 0, 0);
}
__device__ __forceinline__ s8v ld8(const bf_t* p) { return *reinterpret_cast<const s8v*>(p); }

// ---------------- K1: merged norms + weight prep (serial bias blocks first) ----------------
__global__ __launch_bounds__(512) void prep_all_k(
    const float* __restrict__ pair, const float* __restrict__ msa,
    const float* __restrict__ lng_m, const float* __restrict__ lnb_m,
    const float* __restrict__ lng_p, const float* __restrict__ lnb_p,
    const float* __restrict__ Wq, const float* __restrict__ Wk, const float* __restrict__ Wv,
    const float* __restrict__ Wg, const float* __restrict__ Wb, const float* __restrict__ Wo,
    bf_t* __restrict__ pairN, bf_t* __restrict__ msaN, bf_t* __restrict__ wct,
    bf_t* __restrict__ wbt, bf_t* __restrict__ wot, float* __restrict__ bc,
    float* __restrict__ bbp) {
  int b = blockIdx.x;
  int tid = threadIdx.x;
  int lane = tid & 63;
  if (b < 4) {  // bias reductions (latency tail -> start first)
    int ob = b * 4 + (tid >> 7);  // 0..15
    int t = tid & 127;
    if (ob < H_) {
      int h = ob;
      int m = t >> 5, d = t & 31;
      const float* Wsrc = (m == 0) ? Wq : (m == 1) ? Wk : (m == 2) ? Wv : Wg;
      float scale = (m == 0) ? ISC_ : 1.0f;
      float bias = 0.f;
      for (int c = 0; c < CM_; c++)
        bias += lnb_m[h * CM_ + c] * Wsrc[((size_t)h * CM_ + c) * C_ + d];
      bc[h * 128 + t] = bias * scale;
    } else {
      int h = ob - H_;
      float bias = 0.f;
      for (int c = 0; c < CZ_; c++)
        bias += lnb_p[h * CZ_ + c] * Wb[((size_t)h * CZ_ + c) * S_ + t];
      bbp[h * 128 + t] = bias * ISC_;
    }
  } else if (b < 8196) {  // pair norm: 8 rows/block
    int row = (b - 4) * 8 + (tid >> 6);
    float2 v = reinterpret_cast<const float2*>(pair + (size_t)row * CZ_)[lane];
    float s = v.x + v.y;
    float s2 = v.x * v.x + v.y * v.y;
    for (int off = 32; off; off >>= 1) {
      s += __shfl_xor(s, off);
      s2 += __shfl_xor(s2, off);
    }
    float m = s / CZ_;
    float rs = rsqrtf(s2 / CZ_ - m * m + EPS_);
    reinterpret_cast<unsigned*>(pairN)[(size_t)row * 64 + lane] =
        pk2((v.x - m) * rs, (v.y - m) * rs);
  } else if (b < 12292) {  // msa norm: 8 rows/block
    int row = (b - 8196) * 8 + (tid >> 6);
    float4 v = reinterpret_cast<const float4*>(msa + (size_t)row * CM_)[lane];
    float s = v.x + v.y + v.z + v.w;
    float s2 = v.x * v.x + v.y * v.y + v.z * v.z + v.w * v.w;
    for (int off = 32; off; off >>= 1) {
      s += __shfl_xor(s, off);
      s2 += __shfl_xor(s2, off);
    }
    float m = s / CM_;
    float rs = rsqrtf(s2 / CM_ - m * m + EPS_);
    uint2 wv;
    wv.x = pk2((v.x - m) * rs, (v.y - m) * rs);
    wv.y = pk2((v.z - m) * rs, (v.w - m) * rs);
    reinterpret_cast<uint2*>(msaN)[(size_t)row * 64 + lane] = wv;
  } else {  // wide element-wise weight transforms
    int idx = (b - 12292) * 512 + tid;  // 0..458751
    if (idx < 262144) {
      int h = idx >> 15, rem = idx & 32767;
      int j = rem >> 8, c = rem & 255;
      int m = j >> 5, d = j & 31;
      const float* Wsrc = (m == 0) ? Wq : (m == 1) ? Wk : (m == 2) ? Wv : Wg;
      float scale = (m == 0) ? ISC_ : 1.0f;
      wct[idx] = pk1(lng_m[h * CM_ + c] * Wsrc[((size_t)h * CM_ + c) * C_ + d] * scale);
    } else if (idx < 262144 + 131072) {
      int i2 = idx - 262144;
      int h = i2 >> 14, rem = i2 & 16383;
      int t = rem >> 7, c = rem & 127;
      wbt[i2] = pk1(lng_p[h * CZ_ + c] * Wb[((size_t)h * CZ_ + c) * S_ + t] * ISC_);
    } else {
      int i3 = idx - 262144 - 131072;
      int n = i3 >> 8, k = i3 & 255;
      wot[i3] = pk1(Wo[(size_t)k * 256 + n]);
    }
  }
}

// ---------------- K3: qkvg projection via MFMA (r14/r15 proven) ----------------
__global__ __launch_bounds__(512, 1) void qkvg_mfma_k(
    const bf_t* __restrict__ msaN, const bf_t* __restrict__ wct, const float* __restrict__ bc,
    bf_t* __restrict__ q, bf_t* __restrict__ k, bf_t* __restrict__ v, bf_t* __restrict__ g) {
  __shared__ bf_t sm_a[128 * 256];  // 64 KB
  __shared__ bf_t sm_w[128 * 256];  // 64 KB
  int ib = blockIdx.x;
  int tid = threadIdx.x;
  int w = tid >> 6, l = tid & 63;
  int l15 = l & 15, l4 = l >> 4;
  int iw = w >> 2, jw = w & 3;  // per-wave output tile: 64 i x 32 j
  int sr0 = ib * 128;
  int sx7 = l15 & 7;
#pragma unroll
  for (int rep = 0; rep < 8; rep++) {  // pure copy of msaN rows
    int flat = rep * 512 + tid;
    int row = flat >> 5, c = flat & 31;
    *reinterpret_cast<uint4*>(&sm_a[row * 256 + ((c ^ (row & 7)) << 3)]) =
        *reinterpret_cast<const uint4*>(msaN + (size_t)(sr0 + row) * 256 + c * 8);
  }
  for (int h = 0; h < H_; h++) {
    __syncthreads();
#pragma unroll
    for (int rep = 0; rep < 8; rep++) {
      int flat = rep * 512 + tid;
      int row = flat >> 5, c = flat & 31;
      *reinterpret_cast<uint4*>(&sm_w[row * 256 + ((c ^ (row & 7)) << 3)]) =
          *reinterpret_cast<const uint4*>(wct + ((size_t)h * 128 + row) * 256 + c * 8);
    }
    f4v acc[4][2];
#pragma unroll
    for (int jt = 0; jt < 2; jt++) {
      float bb = bc[h * 128 + jw * 32 + jt * 16 + l15];
#pragma unroll
      for (int it = 0; it < 4; it++) acc[it][jt] = f4v{bb, bb, bb, bb};
    }
    __syncthreads();
#pragma unroll
    for (int ks = 0; ks < 8; ks++) {
      int ch = ks * 4 + l4;
      s8v a[4], b[2];
#pragma unroll
      for (int it = 0; it < 4; it++)
        a[it] = ld8(&sm_a[(iw * 64 + it * 16 + l15) * 256 + ((ch ^ sx7) << 3)]);
#pragma unroll
      for (int jt = 0; jt < 2; jt++)
        b[jt] = ld8(&sm_w[(jw * 32 + jt * 16 + l15) * 256 + ((ch ^ sx7) << 3)]);
#pragma unroll
      for (int it = 0; it < 4; it++)
#pragma unroll
        for (int jt = 0; jt < 2; jt++) acc[it][jt] = mfma16(a[it], b[jt], acc[it][jt]);
    }
#pragma unroll
    for (int it = 0; it < 4; it++) {
#pragma unroll
      for (int jt = 0; jt < 2; jt++) {
        int j = jw * 32 + jt * 16 + l15;
        int m_ = j >> 5, d = j & 31;
        bf_t* dst = (m_ == 0) ? q : (m_ == 1) ? k : (m_ == 2) ? v : g;
#pragma unroll
        for (int r = 0; r < 4; r++) {
          int i = iw * 64 + it * 16 + l4 * 4 + r;
          float val = acc[it][jt][r];
          if (m_ == 3) val = 1.f / (1.f + __expf(-val));
          dst[((size_t)h * SR_ + sr0 + i) * C_ + d] = pk1(val);
        }
      }
    }
  }
}

// ---------------- K4: full-MFMA attention, 79.9-KB LDS, 2 blocks/CU ----------------
// XCD-bijective decode (r14). r11/r16-proven chunked core; bounds fixed to (512,2).
// b[h,s,i,j] = pairproj[h, 2s+(i>>7), 2*(i&127)+(j>>7), j&127]
__global__ __launch_bounds__(512, 2) void attn_mfma_k(
    const bf_t* __restrict__ pairN, const bf_t* __restrict__ wbt,
    const float* __restrict__ bbp, const bf_t* __restrict__ qg, const bf_t* __restrict__ kg,
    const bf_t* __restrict__ vg, const bf_t* __restrict__ gg, bf_t* __restrict__ cat) {
  __shared__ bf_t sm_pn[256 * 64];   // pairN K-chunk (i x 64cz), swz   32 KB
  __shared__ bf_t sm_wt[64 * 64];    // wbt K-chunk (j x 64cz), swz      8 KB
  __shared__ bf_t sm_p[256 * 64];    // P (i x j_local), swz            32 KB
  __shared__ bf_t sm_vt[32 * 64];    // v^T tile (d x j), swz            4 KB
  __shared__ float sm_redm[4 * 64];
  __shared__ float sm_reds[4 * 64];  // total 79,872 B -> 2 blocks/CU

  // XCD-bijective (s,h) decode
  int b = blockIdx.x;
  int x = b & 7, tq = b >> 3;
  int round = tq >> 5, inner = tq & 31;
  int sl = inner >> 3, h = inner & 7;
  int s = (round * 8 + x) * 4 + sl;

  int tid = threadIdx.x;
  int w = tid >> 6, l = tid & 63;
  int l15 = l & 15, l4 = l >> 4, sx7 = l15 & 7;
  int iw = w >> 1, jw = w & 1, dw = w & 1;
  size_t base = ((size_t)h * SR_ + (size_t)s * R_) * C_;  // bf16 elems
  const bf_t* wbh = wbt + (size_t)h * 128 * 128;

  // q fragments in registers (pass-invariant, coalesced 16-row reads)
  s8v qa[4];
#pragma unroll
  for (int it = 0; it < 4; it++)
    qa[it] = ld8(&qg[base + (size_t)(iw * 64 + it * 16 + l15) * C_ + l4 * 8]);

  f4v accO[4];
#pragma unroll
  for (int it = 0; it < 4; it++) accO[it] = f4v{0.f, 0.f, 0.f, 0.f};

  for (int pass = 0; pass < 4; pass++) {
    int p = pass >> 1, jh = pass & 1;
    int j0 = p * 128 + jh * 64;
    // k frags issued EARLY (global, coalesced); in flight across staging
    s8v kb0 = ld8(&kg[base + (size_t)(j0 + jw * 32 + l15) * C_ + l4 * 8]);
    s8v kb1 = ld8(&kg[base + (size_t)(j0 + jw * 32 + 16 + l15) * C_ + l4 * 8]);
    __syncthreads();  // (A) prev AV done; vt/pn/wt reusable
    if (tid >= 256) {  // stage vT: transpose 64x32 -> 32x64 (read at AV, post-F)
      int t2 = tid - 256;
      int j = t2 >> 2, dc = t2 & 3;
      uint4 u = *reinterpret_cast<const uint4*>(vg + base + (size_t)(j0 + j) * C_ + dc * 8);
      unsigned uu[4] = {u.x, u.y, u.z, u.w};
#pragma unroll
      for (int e = 0; e < 8; e++) {
        int d = dc * 8 + e;
        bf_t val = (bf_t)((uu[e >> 1] >> ((e & 1) * 16)) & 0xffff);
        sm_vt[d * 64 + ((((j >> 3) ^ (d & 7)) << 3) + (j & 7))] = val;
      }
    }
    f4v acc[4][2];
    {
      float bb0 = bbp[h * 128 + jh * 64 + jw * 32 + l15];
      float bb1 = bbp[h * 128 + jh * 64 + jw * 32 + 16 + l15];
#pragma unroll
      for (int it = 0; it < 4; it++) {
        acc[it][0] = f4v{bb0, bb0, bb0, bb0};
        acc[it][1] = f4v{bb1, bb1, bb1, bb1};
      }
    }
    // ---- pair-bias GEMM: K=128 in 2 staged chunks of 64 (r11/r16-proven) ----
#pragma unroll
    for (int kc = 0; kc < 2; kc++) {
#pragma unroll
      for (int rep = 0; rep < 4; rep++) {  // stage pN chunk (256 rows x 64 cz)
        int idx = rep * 512 + tid;
        int row = idx >> 3, c8 = idx & 7;
        int gr = (2 * s + (row >> 7)) * 256 + 2 * (row & 127) + p;
        *reinterpret_cast<uint4*>(&sm_pn[row * 64 + ((c8 ^ (row & 7)) << 3)]) =
            *reinterpret_cast<const uint4*>(pairN + (size_t)gr * 128 + kc * 64 + c8 * 8);
      }
      {  // stage wt chunk (64 rows x 64 cz)
        int row = tid >> 3, c8 = tid & 7;
        *reinterpret_cast<uint4*>(&sm_wt[row * 64 + ((c8 ^ (row & 7)) << 3)]) =
            *reinterpret_cast<const uint4*>(wbh + (size_t)(jh * 64 + row) * 128 + kc * 64 +
                                            c8 * 8);
      }
      __syncthreads();  // (B/D) chunk staged
#pragma unroll
      for (int ks = 0; ks < 2; ks++) {
        int ch = ks * 4 + l4;
        s8v a[4], b2[2];
#pragma unroll
        for (int it = 0; it < 4; it++)
          a[it] = ld8(&sm_pn[(iw * 64 + it * 16 + l15) * 64 + ((ch ^ sx7) << 3)]);
#pragma unroll
        for (int u = 0; u < 2; u++)
          b2[u] = ld8(&sm_wt[(jw * 32 + u * 16 + l15) * 64 + ((ch ^ sx7) << 3)]);
#pragma unroll
        for (int it = 0; it < 4; it++) {
          acc[it][0] = mfma16(a[it], b2[0], acc[it][0]);
          acc[it][1] = mfma16(a[it], b2[1], acc[it][1]);
        }
      }
      if (kc == 0) __syncthreads();  // (C) chunk0 consumed before restage
    }
    // ---- QK^T: q regs x k global frags ----
#pragma unroll
    for (int it = 0; it < 4; it++) {
      acc[it][0] = mfma16(qa[it], kb0, acc[it][0]);
      acc[it][1] = mfma16(qa[it], kb1, acc[it][1]);
    }
    // ---- softmax over i: per-wave max + rescaled sums (one barrier) ----
    float fac[2], mloc[2];
#pragma unroll
    for (int u = 0; u < 2; u++) {
      float m0 = -1e30f;
#pragma unroll
      for (int it = 0; it < 4; it++)
#pragma unroll
        for (int r = 0; r < 4; r++) m0 = fmaxf(m0, acc[it][u][r]);
      m0 = fmaxf(m0, __shfl_xor(m0, 16));
      m0 = fmaxf(m0, __shfl_xor(m0, 32));
      float s0 = 0.f;
#pragma unroll
      for (int it = 0; it < 4; it++)
#pragma unroll
        for (int r = 0; r < 4; r++) {
          float e = __expf(acc[it][u][r] - m0);
          acc[it][u][r] = e;
          s0 += e;
        }
      s0 += __shfl_xor(s0, 16);
      s0 += __shfl_xor(s0, 32);
      mloc[u] = m0;
      if (l < 16) {
        sm_redm[iw * 64 + jw * 32 + u * 16 + l] = m0;
        sm_reds[iw * 64 + jw * 32 + u * 16 + l] = s0;
      }
    }
    __syncthreads();  // (E) reductions visible
#pragma unroll
    for (int u = 0; u < 2; u++) {
      int jc = jw * 32 + u * 16 + l15;
      float M = fmaxf(fmaxf(sm_redm[jc], sm_redm[64 + jc]),
                      fmaxf(sm_redm[128 + jc], sm_redm[192 + jc]));
      float tot = 0.f;
#pragma unroll
      for (int gx = 0; gx < 4; gx++)
        tot += sm_reds[gx * 64 + jc] * __expf(sm_redm[gx * 64 + jc] - M);
      fac[u] = __expf(mloc[u] - M) / tot;
#pragma unroll
      for (int it = 0; it < 4; it++)
#pragma unroll
        for (int r = 0; r < 4; r++) {
          int i = iw * 64 + it * 16 + l4 * 4 + r;
          sm_p[i * 64 + ((((jc >> 3) ^ (i & 7)) << 3) + (jc & 7))] =
              pk1(acc[it][u][r] * fac[u]);
        }
    }
    __syncthreads();  // (F) P + vT ready
    // ---- AV: O += P.V  (K=64: 2 ksteps) ----
#pragma unroll
    for (int ks = 0; ks < 2; ks++) {
      int ch = ks * 4 + l4;
      s8v vb = ld8(&sm_vt[(dw * 16 + l15) * 64 + ((ch ^ sx7) << 3)]);
#pragma unroll
      for (int it = 0; it < 4; it++) {
        s8v pa = ld8(&sm_p[(iw * 64 + it * 16 + l15) * 64 + ((ch ^ sx7) << 3)]);
        accO[it] = mfma16(pa, vb, accO[it]);
      }
    }
  }
  // ---- epilogue: gate and write cat ----
#pragma unroll
  for (int it = 0; it < 4; it++) {
#pragma unroll
    for (int r = 0; r < 4; r++) {
      int i = iw * 64 + it * 16 + l4 * 4 + r;
      int d = dw * 16 + l15;
      float gf = uplo((unsigned)gg[base + (size_t)i * C_ + d]);
      cat[((size_t)s * R_ + i) * 256 + h * 32 + d] = pk1(accO[it][r] * gf);
    }
  }
}

// ---------------- K6: output projection via MFMA (r9 proven) ----------------
__global__ __launch_bounds__(512, 1) void out_mfma_k(const bf_t* __restrict__ cat,
                                                     const bf_t* __restrict__ wot,
                                                     const float* __restrict__ bo,
                                                     float* __restrict__ out) {
  __shared__ bf_t sm_a[128 * 256];  // 64 KB
  __shared__ bf_t sm_b[128 * 256];  // 64 KB
  int ib = blockIdx.x;
  int tid = threadIdx.x;
  int w = tid >> 6, l = tid & 63;
  int l15 = l & 15, l4 = l >> 4, sx7 = l15 & 7;
  int iw = w >> 2, jw = w & 3;  // 64 i x 32 n per wave
  int sr0 = ib * 128;
#pragma unroll
  for (int rep = 0; rep < 8; rep++) {  // stage A (cat) once
    int flat = rep * 512 + tid;
    int row = flat >> 5, c = flat & 31;
    *reinterpret_cast<uint4*>(&sm_a[row * 256 + ((c ^ (row & 7)) << 3)]) =
        *reinterpret_cast<const uint4*>(cat + (size_t)(sr0 + row) * 256 + c * 8);
  }
  for (int nb = 0; nb < 2; nb++) {
    __syncthreads();  // A ready (nb=0); prev sm_b readers done (nb=1)
#pragma unroll
    for (int rep = 0; rep < 8; rep++) {  // stage WoT rows nb*128..+128
      int flat = rep * 512 + tid;
      int row = flat >> 5, c = flat & 31;
      *reinterpret_cast<uint4*>(&sm_b[row * 256 + ((c ^ (row & 7)) << 3)]) =
          *reinterpret_cast<const uint4*>(wot + (size_t)(nb * 128 + row) * 256 + c * 8);
    }
    f4v acc[4][2];
#pragma unroll
    for (int jt = 0; jt < 2; jt++) {
      float bb = bo[nb * 128 + jw * 32 + jt * 16 + l15];
#pragma unroll
      for (int it = 0; it < 4; it++) acc[it][jt] = f4v{bb, bb, bb, bb};
    }
    __syncthreads();  // B ready
#pragma unroll
    for (int ks = 0; ks < 8; ks++) {
      int ch = ks * 4 + l4;
      s8v a[4], b[2];
#pragma unroll
      for (int it = 0; it < 4; it++)
        a[it] = ld8(&sm_a[(iw * 64 + it * 16 + l15) * 256 + ((ch ^ sx7) << 3)]);
#pragma unroll
      for (int jt = 0; jt < 2; jt++)
        b[jt] = ld8(&sm_b[(jw * 32 + jt * 16 + l15) * 256 + ((ch ^ sx7) << 3)]);
#pragma unroll
      for (int it = 0; it < 4; it++)
#pragma unroll
        for (int jt = 0; jt < 2; jt++) acc[it][jt] = mfma16(a[it], b[jt], acc[it][jt]);
    }
#pragma unroll
    for (int it = 0; it < 4; it++)
#pragma unroll
      for (int jt = 0; jt < 2; jt++) {
        int n = nb * 128 + jw * 32 + jt * 16 + l15;
#pragma unroll
        for (int r = 0; r < 4; r++) {
          int i = iw * 64 + it * 16 + l4 * 4 + r;
          out[(size_t)(sr0 + i) * 256 + n] = acc[it][jt][r];
        }
      }
  }
}

extern "C" void kernel_launch(void* const* d_in, const int* in_sizes, int n_in, void* d_out,
                              int out_size, void* d_ws, size_t ws_size, hipStream_t stream) {
  if (ws_size < NEED_BYTES) return;  // diagnostic clean-fail (absmax would read 0.1309)

  const float* msa = (const float*)d_in[0];
  const float* pair = (const float*)d_in[1];
  const float* lng_m = (const float*)d_in[2];
  const float* lnb_m = (const float*)d_in[3];
  const float* lng_p = (const float*)d_in[4];
  const float* lnb_p = (const float*)d_in[5];
  const float* Wq = (const float*)d_in[6];
  const float* Wk = (const float*)d_in[7];
  const float* Wv = (const float*)d_in[8];
  const float* Wg = (const float*)d_in[9];
  const float* Wb = (const float*)d_in[10];
  const float* Wo = (const float*)d_in[11];
  const float* bo = (const float*)d_in[12];
  float* out = (float*)d_out;
  float* ws = (float*)d_ws;

  bf_t* wct = (bf_t*)(ws + OFF_WC);
  float* bc = ws + OFF_BC;
  float* bbp = ws + OFF_BBP;
  bf_t* qb = (bf_t*)((char*)d_ws + BF_BASE);
  bf_t* kb = qb + QKVG_ELEMS;
  bf_t* vb = kb + QKVG_ELEMS;
  bf_t* gb = vb + QKVG_ELEMS;
  bf_t* cat = gb + QKVG_ELEMS;
  bf_t* wbt = cat + CAT_ELEMS;
  bf_t* wot = wbt + WBT_ELEMS;
  bf_t* pairN = wot + WOT_ELEMS;
  bf_t* msaN = pairN + PAIRN_ELEMS;

  prep_all_k<<<13188, 512, 0, stream>>>(pair, msa, lng_m, lnb_m, lng_p, lnb_p, Wq, Wk, Wv, Wg,
                                        Wb, Wo, pairN, msaN, wct, wbt, wot, bc, bbp);
  qkvg_mfma_k<<<SR_ / 128, 512, 0, stream>>>(msaN, wct, bc, qb, kb, vb, gb);
  attn_mfma_k<<<S_ * H_, 512, 0, stream>>>(pairN, wbt, bbp, qb, kb, vb, gb, cat);
  out_mfma_k<<<SR_ / 128, 512, 0, stream>>>(cat, wot, bo, out);
}